// Round 2
// baseline (446.343 us; speedup 1.0000x reference)
//
#include <hip/hip_runtime.h>

// CombinedActorModel: B=1M, A=3.
// One thread per batch element. Fully unrolled fp32; weights are wave-uniform
// -> scalar s_load + FMA-with-SGPR-operand. Wlin+softsign+Wout fused into a
// single stream (no h[25] array); actors combined via online softmax (11 regs
// instead of 30). LDS used only to coalesce the stride-108B spatial loads and
// stride-36B output stores.
// __launch_bounds__(256,4): <=128 VGPRs, 4 waves/SIMD — live set ~85 floats,
// prevents the R1 spill-to-scratch (VGPR=56 allocator squeeze).

__global__ __launch_bounds__(256, 4) void actor_fused(
    const float* __restrict__ spatial,
    const float* __restrict__ Wmx, const float* __restrict__ bmx,
    const float* __restrict__ Wnx, const float* __restrict__ bnx,
    const float* __restrict__ Wmy, const float* __restrict__ bmy,
    const float* __restrict__ Wny, const float* __restrict__ bny,
    const float* __restrict__ Wmz, const float* __restrict__ bmz,
    const float* __restrict__ Wnz, const float* __restrict__ bnz,
    const float* __restrict__ Wlin, const float* __restrict__ blin,
    const float* __restrict__ Wout, const float* __restrict__ bout,
    float* __restrict__ out)
{
    __shared__ float lds[6912];           // 256 elems * 27 floats = 27648 B
    const int t  = threadIdx.x;
    const int b0 = blockIdx.x * 256;

    // ---- coalesced global -> LDS staging of spatial (1728 float4 per block)
    const float4* gsrc = (const float4*)(spatial + (size_t)b0 * 27);
    float4* lds4 = (float4*)lds;
    #pragma unroll
    for (int k = 0; k < 7; ++k) {
        int idx = t + k * 256;
        if (idx < 1728) lds4[idx] = gsrc[idx];
    }
    __syncthreads();

    // per-thread feature vector (stride 27 in LDS: gcd(27,32)=1 -> conflict-free)
    float s[27];
    #pragma unroll
    for (int i = 0; i < 27; ++i) s[i] = lds[t * 27 + i];

    // online-softmax running state across actors
    float run_m = -1e30f, run_l = 0.0f;
    float run_acc[9];
    #pragma unroll
    for (int j = 0; j < 9; ++j) run_acc[j] = 0.0f;

    #pragma unroll
    for (int a = 0; a < 3; ++a) {
        float ps[25];

        // plane x: (s[0:6]@Wmx^T + bmx) * (s[6:9]@Wnx^T + bnx), 10 outputs
        #pragma unroll
        for (int o = 0; o < 10; ++o) {
            float m = bmx[a*10 + o];
            #pragma unroll
            for (int i = 0; i < 6; ++i) m = fmaf(s[i], Wmx[(a*10 + o)*6 + i], m);
            float n = bnx[a*10 + o];
            #pragma unroll
            for (int i = 0; i < 3; ++i) n = fmaf(s[6 + i], Wnx[(a*10 + o)*3 + i], n);
            ps[o] = m * n;
        }
        // plane y
        #pragma unroll
        for (int o = 0; o < 10; ++o) {
            float m = bmy[a*10 + o];
            #pragma unroll
            for (int i = 0; i < 6; ++i) m = fmaf(s[9 + i], Wmy[(a*10 + o)*6 + i], m);
            float n = bny[a*10 + o];
            #pragma unroll
            for (int i = 0; i < 3; ++i) n = fmaf(s[15 + i], Wny[(a*10 + o)*3 + i], n);
            ps[10 + o] = m * n;
        }
        // plane z: 5 outputs
        #pragma unroll
        for (int o = 0; o < 5; ++o) {
            float m = bmz[a*5 + o];
            #pragma unroll
            for (int i = 0; i < 6; ++i) m = fmaf(s[18 + i], Wmz[(a*5 + o)*6 + i], m);
            float n = bnz[a*5 + o];
            #pragma unroll
            for (int i = 0; i < 3; ++i) n = fmaf(s[24 + i], Wnz[(a*5 + o)*3 + i], n);
            ps[20 + o] = m * n;
        }

        // fused Wlin + softsign + Wout (rows 0..9 only; 10..14 are dead)
        float acc[10];
        #pragma unroll
        for (int r = 0; r < 10; ++r) acc[r] = bout[a*15 + r];

        #pragma unroll
        for (int o = 0; o < 25; ++o) {
            float v = blin[a*25 + o];
            #pragma unroll
            for (int d = 0; d < 25; ++d)
                v = fmaf(ps[d], Wlin[(a*25 + o)*25 + d], v);
            float hs = v * __builtin_amdgcn_rcpf(1.0f + fabsf(v));  // softsign
            #pragma unroll
            for (int r = 0; r < 10; ++r)
                acc[r] = fmaf(hs, Wout[(a*15 + r)*25 + o], acc[r]);
        }

        // online softmax update (channel 9 is the gate)
        float v  = acc[9];
        float nm = fmaxf(run_m, v);
        float alpha = __expf(run_m - nm);
        float e     = __expf(v - nm);
        run_l = fmaf(run_l, alpha, e);
        #pragma unroll
        for (int j = 0; j < 9; ++j)
            run_acc[j] = fmaf(run_acc[j], alpha, e * acc[j]);
        run_m = nm;
    }

    const float inv_l = __builtin_amdgcn_rcpf(run_l);

    // ---- stage outputs in LDS, store coalesced (576 float4 per block)
    __syncthreads();
    #pragma unroll
    for (int j = 0; j < 9; ++j) lds[t * 9 + j] = run_acc[j] * inv_l;
    __syncthreads();

    float4* gdst = (float4*)(out + (size_t)b0 * 9);
    #pragma unroll
    for (int k = 0; k < 3; ++k) {
        int idx = t + k * 256;
        if (idx < 576) gdst[idx] = lds4[idx];
    }
}

extern "C" void kernel_launch(void* const* d_in, const int* in_sizes, int n_in,
                              void* d_out, int out_size, void* d_ws, size_t ws_size,
                              hipStream_t stream) {
    const float* spatial = (const float*)d_in[0];
    // d_in[1] = car_stats: unused by the model, never read.
    const float* Wmx  = (const float*)d_in[2];
    const float* bmx  = (const float*)d_in[3];
    const float* Wnx  = (const float*)d_in[4];
    const float* bnx  = (const float*)d_in[5];
    const float* Wmy  = (const float*)d_in[6];
    const float* bmy  = (const float*)d_in[7];
    const float* Wny  = (const float*)d_in[8];
    const float* bny  = (const float*)d_in[9];
    const float* Wmz  = (const float*)d_in[10];
    const float* bmz  = (const float*)d_in[11];
    const float* Wnz  = (const float*)d_in[12];
    const float* bnz  = (const float*)d_in[13];
    const float* Wlin = (const float*)d_in[14];
    const float* blin = (const float*)d_in[15];
    const float* Wout = (const float*)d_in[16];
    const float* bout = (const float*)d_in[17];
    float* out = (float*)d_out;

    const int nb = in_sizes[0] / 27;          // 1048576, multiple of 256
    dim3 grid(nb / 256);
    actor_fused<<<grid, dim3(256), 0, stream>>>(
        spatial,
        Wmx, bmx, Wnx, bnx,
        Wmy, bmy, Wny, bny,
        Wmz, bmz, Wnz, bnz,
        Wlin, blin, Wout, bout,
        out);
}

// Round 3
// 368.312 us; speedup vs baseline: 1.2119x; 1.2119x over previous
//
#include <hip/hip_runtime.h>

// CombinedActorModel: B=1M, A=3. One thread per element.
// R3: anti-spill restructure. R1/R2 counters showed ~9700 VALU ops/elem vs
// ~3500 needed with VGPR_Count pinned at 52-56 -> register allocator was
// churning the big live arrays through spill moves. Fixes:
//  - peak live ~75 floats: s read as 9-float plane slices from LDS,
//    h[25] materialized once, separate row-major Wout pass, online softmax
//    (11 regs) instead of o9[3][10].
//  - amdgpu_waves_per_eu(2): budget 256 VGPRs (2 waves/SIMD), removes the
//    occupancy-chasing squeeze. 8 waves/CU is plenty: 25 independent FMA
//    chains per loop saturate the SIMD issue from a single wave.
//  - weights indexed with compile-time constants, row-major -> contiguous
//    s_load_dwordx16 streams on the scalar pipe, FMA takes SGPR operand.
// LDS only for coalescing the 108B-stride input and 36B-stride output.

__global__ __launch_bounds__(256)
__attribute__((amdgpu_waves_per_eu(2)))
void actor_fused(
    const float* __restrict__ spatial,
    const float* __restrict__ Wmx, const float* __restrict__ bmx,
    const float* __restrict__ Wnx, const float* __restrict__ bnx,
    const float* __restrict__ Wmy, const float* __restrict__ bmy,
    const float* __restrict__ Wny, const float* __restrict__ bny,
    const float* __restrict__ Wmz, const float* __restrict__ bmz,
    const float* __restrict__ Wnz, const float* __restrict__ bnz,
    const float* __restrict__ Wlin, const float* __restrict__ blin,
    const float* __restrict__ Wout, const float* __restrict__ bout,
    float* __restrict__ out)
{
    __shared__ float lds[6912];           // 256 * 27 floats = 27648 B
    const int t  = threadIdx.x;
    const size_t b0 = (size_t)blockIdx.x * 256;

    // coalesced global -> LDS staging of spatial (1728 float4 per block)
    const float4* gsrc = (const float4*)(spatial + b0 * 27);
    float4* lds4 = (float4*)lds;
    #pragma unroll
    for (int k = 0; k < 7; ++k) {
        int idx = t + k * 256;
        if (idx < 1728) lds4[idx] = gsrc[idx];
    }
    __syncthreads();

    // online-softmax running state across actors (11 regs)
    float run_m = -3.0e38f, run_l = 0.0f;
    float run_acc[9];
    #pragma unroll
    for (int j = 0; j < 9; ++j) run_acc[j] = 0.0f;

    #pragma unroll
    for (int a = 0; a < 3; ++a) {
        float ps[25];

        // ---- plane x: only s[0:9] live
        {
            float sx[9];
            #pragma unroll
            for (int i = 0; i < 9; ++i) sx[i] = lds[t * 27 + i];
            #pragma unroll
            for (int o = 0; o < 10; ++o) {
                float m = bmx[a*10 + o];
                #pragma unroll
                for (int i = 0; i < 6; ++i) m = fmaf(sx[i], Wmx[(a*10 + o)*6 + i], m);
                float n = bnx[a*10 + o];
                #pragma unroll
                for (int i = 0; i < 3; ++i) n = fmaf(sx[6 + i], Wnx[(a*10 + o)*3 + i], n);
                ps[o] = m * n;
            }
        }
        // ---- plane y: only s[9:18] live
        {
            float sy[9];
            #pragma unroll
            for (int i = 0; i < 9; ++i) sy[i] = lds[t * 27 + 9 + i];
            #pragma unroll
            for (int o = 0; o < 10; ++o) {
                float m = bmy[a*10 + o];
                #pragma unroll
                for (int i = 0; i < 6; ++i) m = fmaf(sy[i], Wmy[(a*10 + o)*6 + i], m);
                float n = bny[a*10 + o];
                #pragma unroll
                for (int i = 0; i < 3; ++i) n = fmaf(sy[6 + i], Wny[(a*10 + o)*3 + i], n);
                ps[10 + o] = m * n;
            }
        }
        // ---- plane z: only s[18:27] live
        {
            float sz[9];
            #pragma unroll
            for (int i = 0; i < 9; ++i) sz[i] = lds[t * 27 + 18 + i];
            #pragma unroll
            for (int o = 0; o < 5; ++o) {
                float m = bmz[a*5 + o];
                #pragma unroll
                for (int i = 0; i < 6; ++i) m = fmaf(sz[i], Wmz[(a*5 + o)*6 + i], m);
                float n = bnz[a*5 + o];
                #pragma unroll
                for (int i = 0; i < 3; ++i) n = fmaf(sz[6 + i], Wnz[(a*5 + o)*3 + i], n);
                ps[20 + o] = m * n;
            }
        }

        // ---- 25x25 linear + softsign (row-major weight stream)
        float h[25];
        #pragma unroll
        for (int o = 0; o < 25; ++o) {
            float v = blin[a*25 + o];
            #pragma unroll
            for (int d = 0; d < 25; ++d)
                v = fmaf(ps[d], Wlin[(a*25 + o)*25 + d], v);
            h[o] = v * __builtin_amdgcn_rcpf(1.0f + fabsf(v));
        }

        // ---- head rows 0..9 (10..14 are dead), row-major
        float acc[10];
        #pragma unroll
        for (int r = 0; r < 10; ++r) {
            float v = bout[a*15 + r];
            #pragma unroll
            for (int o = 0; o < 25; ++o)
                v = fmaf(h[o], Wout[(a*15 + r)*25 + o], v);
            acc[r] = v;
        }

        // ---- online softmax update (channel 9 gates)
        float g  = acc[9];
        float nm = fmaxf(run_m, g);
        float alpha = __expf(run_m - nm);
        float e     = __expf(g - nm);
        run_l = fmaf(run_l, alpha, e);
        #pragma unroll
        for (int j = 0; j < 9; ++j)
            run_acc[j] = fmaf(run_acc[j], alpha, e * acc[j]);
        run_m = nm;
    }

    const float inv_l = __builtin_amdgcn_rcpf(run_l);

    // stage outputs in LDS, store coalesced (576 float4 per block)
    __syncthreads();
    #pragma unroll
    for (int j = 0; j < 9; ++j) lds[t * 9 + j] = run_acc[j] * inv_l;
    __syncthreads();

    float4* gdst = (float4*)(out + b0 * 9);
    #pragma unroll
    for (int k = 0; k < 3; ++k) {
        int idx = t + k * 256;
        if (idx < 576) gdst[idx] = lds4[idx];
    }
}

extern "C" void kernel_launch(void* const* d_in, const int* in_sizes, int n_in,
                              void* d_out, int out_size, void* d_ws, size_t ws_size,
                              hipStream_t stream) {
    const float* spatial = (const float*)d_in[0];
    // d_in[1] = car_stats: unused by the model, never read.
    const float* Wmx  = (const float*)d_in[2];
    const float* bmx  = (const float*)d_in[3];
    const float* Wnx  = (const float*)d_in[4];
    const float* bnx  = (const float*)d_in[5];
    const float* Wmy  = (const float*)d_in[6];
    const float* bmy  = (const float*)d_in[7];
    const float* Wny  = (const float*)d_in[8];
    const float* bny  = (const float*)d_in[9];
    const float* Wmz  = (const float*)d_in[10];
    const float* bmz  = (const float*)d_in[11];
    const float* Wnz  = (const float*)d_in[12];
    const float* bnz  = (const float*)d_in[13];
    const float* Wlin = (const float*)d_in[14];
    const float* blin = (const float*)d_in[15];
    const float* Wout = (const float*)d_in[16];
    const float* bout = (const float*)d_in[17];
    float* out = (float*)d_out;

    const int nb = in_sizes[0] / 27;          // 1048576, multiple of 256
    dim3 grid(nb / 256);
    actor_fused<<<grid, dim3(256), 0, stream>>>(
        spatial,
        Wmx, bmx, Wnx, bnx,
        Wmy, bmy, Wny, bny,
        Wmz, bmz, Wnz, bnz,
        Wlin, blin, Wout, bout,
        out);
}

// Round 4
// 290.885 us; speedup vs baseline: 1.5344x; 1.2662x over previous
//
#include <hip/hip_runtime.h>

// CombinedActorModel: B=1M, A=3.
// R4: actor-per-wave. Block = 192 threads = 3 waves; wave a computes actor a
// for 64 batch elements. Rationale (R1-R3 counters): one-thread-per-element
// had ~107 live floats + 15.6KB uniform weight stream per wave -> allocator
// pinned 56 arch VGPRs and churned arrays through AGPR moves (VALU-busy time
// 2.7x the FMA floor, zero scratch traffic). Per-actor split cuts live state
// to ~45 floats and weight stream to 5.2KB/wave.
// Prep kernel transposes Wout rows 0..9 into d_ws so the Wout accumulate
// fuses into the Wlin loop with contiguous scalar loads (no h[25]).
// Cross-actor softmax via LDS (stride 11 = conflict-free), wave 0 combines.

__global__ void prep_woutT(const float* __restrict__ Wout, float* __restrict__ woutT) {
    int i = threadIdx.x + blockIdx.x * blockDim.x;   // 750 = 3*25*10
    if (i < 750) {
        int a = i / 250, rem = i % 250, o = rem / 10, r = rem % 10;
        // woutT[a][o][r] = Wout[a][r][o]
        woutT[i] = Wout[a * 375 + r * 25 + o];
    }
}

__global__ __launch_bounds__(192) void actor_fused(
    const float* __restrict__ spatial,
    const float* __restrict__ Wmx, const float* __restrict__ bmx,
    const float* __restrict__ Wnx, const float* __restrict__ bnx,
    const float* __restrict__ Wmy, const float* __restrict__ bmy,
    const float* __restrict__ Wny, const float* __restrict__ bny,
    const float* __restrict__ Wmz, const float* __restrict__ bmz,
    const float* __restrict__ Wnz, const float* __restrict__ bnz,
    const float* __restrict__ Wlin, const float* __restrict__ blin,
    const float* __restrict__ woutT, const float* __restrict__ bout,
    float* __restrict__ out)
{
    __shared__ float lds_s[1728];    // 64 elems * 27 feats
    __shared__ float lds_acc[1408];  // 2 actors * 64 elems * 11 (pad)
    __shared__ float lds_o[576];     // 64 elems * 9 outputs

    const int t = threadIdx.x;
    const int l = t & 63;                                  // element lane
    const int a = __builtin_amdgcn_readfirstlane(t >> 6);  // actor = wave id (uniform)
    const size_t b0 = (size_t)blockIdx.x * 64;             // first element of block

    // ---- coalesced global -> LDS staging: 432 float4 per block
    {
        const float4* gsrc = (const float4*)(spatial + b0 * 27);
        float4* dst4 = (float4*)lds_s;
        #pragma unroll
        for (int k = 0; k < 3; ++k) {
            int idx = t + k * 192;
            if (idx < 432) dst4[idx] = gsrc[idx];
        }
    }
    __syncthreads();

    // ---- this wave's actor chain for element l
    float ps[25];

    {   // plane x: s[0:9]
        float sx[9];
        #pragma unroll
        for (int i = 0; i < 9; ++i) sx[i] = lds_s[l * 27 + i];
        #pragma unroll
        for (int o = 0; o < 10; ++o) {
            float m = bmx[a * 10 + o];
            #pragma unroll
            for (int i = 0; i < 6; ++i) m = fmaf(sx[i], Wmx[(a * 10 + o) * 6 + i], m);
            float n = bnx[a * 10 + o];
            #pragma unroll
            for (int i = 0; i < 3; ++i) n = fmaf(sx[6 + i], Wnx[(a * 10 + o) * 3 + i], n);
            ps[o] = m * n;
        }
    }
    {   // plane y: s[9:18]
        float sy[9];
        #pragma unroll
        for (int i = 0; i < 9; ++i) sy[i] = lds_s[l * 27 + 9 + i];
        #pragma unroll
        for (int o = 0; o < 10; ++o) {
            float m = bmy[a * 10 + o];
            #pragma unroll
            for (int i = 0; i < 6; ++i) m = fmaf(sy[i], Wmy[(a * 10 + o) * 6 + i], m);
            float n = bny[a * 10 + o];
            #pragma unroll
            for (int i = 0; i < 3; ++i) n = fmaf(sy[6 + i], Wny[(a * 10 + o) * 3 + i], n);
            ps[10 + o] = m * n;
        }
    }
    {   // plane z: s[18:27]
        float sz[9];
        #pragma unroll
        for (int i = 0; i < 9; ++i) sz[i] = lds_s[l * 27 + 18 + i];
        #pragma unroll
        for (int o = 0; o < 5; ++o) {
            float m = bmz[a * 5 + o];
            #pragma unroll
            for (int i = 0; i < 6; ++i) m = fmaf(sz[i], Wmz[(a * 5 + o) * 6 + i], m);
            float n = bnz[a * 5 + o];
            #pragma unroll
            for (int i = 0; i < 3; ++i) n = fmaf(sz[6 + i], Wnz[(a * 5 + o) * 3 + i], n);
            ps[20 + o] = m * n;
        }
    }

    // ---- fused Wlin + softsign + WoutT accumulate (head rows 0..9)
    float acc[10];
    #pragma unroll
    for (int r = 0; r < 10; ++r) acc[r] = bout[a * 15 + r];

    #pragma unroll
    for (int o = 0; o < 25; ++o) {
        float v = blin[a * 25 + o];
        #pragma unroll
        for (int d = 0; d < 25; ++d)
            v = fmaf(ps[d], Wlin[(a * 25 + o) * 25 + d], v);
        float hs = v * __builtin_amdgcn_rcpf(1.0f + fabsf(v));   // softsign
        #pragma unroll
        for (int r = 0; r < 10; ++r)
            acc[r] = fmaf(hs, woutT[a * 250 + o * 10 + r], acc[r]);
    }

    // ---- cross-actor combine: waves 1,2 park acc in LDS, wave 0 reduces
    __syncthreads();
    if (a > 0) {
        #pragma unroll
        for (int r = 0; r < 10; ++r)
            lds_acc[(a - 1) * 704 + l * 11 + r] = acc[r];
    }
    __syncthreads();
    if (a == 0) {
        float a1[10], a2[10];
        #pragma unroll
        for (int r = 0; r < 10; ++r) a1[r] = lds_acc[l * 11 + r];
        #pragma unroll
        for (int r = 0; r < 10; ++r) a2[r] = lds_acc[704 + l * 11 + r];

        float mx = fmaxf(acc[9], fmaxf(a1[9], a2[9]));
        float e0 = __expf(acc[9] - mx);
        float e1 = __expf(a1[9] - mx);
        float e2 = __expf(a2[9] - mx);
        float inv = __builtin_amdgcn_rcpf(e0 + e1 + e2);
        #pragma unroll
        for (int j = 0; j < 9; ++j)
            lds_o[l * 9 + j] = (acc[j] * e0 + a1[j] * e1 + a2[j] * e2) * inv;
    }
    __syncthreads();

    // ---- coalesced store: 144 float4 per block
    {
        float4* gdst = (float4*)(out + b0 * 9);
        const float4* src4 = (const float4*)lds_o;
        if (t < 144) gdst[t] = src4[t];
    }
}

extern "C" void kernel_launch(void* const* d_in, const int* in_sizes, int n_in,
                              void* d_out, int out_size, void* d_ws, size_t ws_size,
                              hipStream_t stream) {
    const float* spatial = (const float*)d_in[0];
    // d_in[1] = car_stats: unused by the model, never read.
    const float* Wmx  = (const float*)d_in[2];
    const float* bmx  = (const float*)d_in[3];
    const float* Wnx  = (const float*)d_in[4];
    const float* bnx  = (const float*)d_in[5];
    const float* Wmy  = (const float*)d_in[6];
    const float* bmy  = (const float*)d_in[7];
    const float* Wny  = (const float*)d_in[8];
    const float* bny  = (const float*)d_in[9];
    const float* Wmz  = (const float*)d_in[10];
    const float* bmz  = (const float*)d_in[11];
    const float* Wnz  = (const float*)d_in[12];
    const float* bnz  = (const float*)d_in[13];
    const float* Wlin = (const float*)d_in[14];
    const float* blin = (const float*)d_in[15];
    const float* Wout = (const float*)d_in[16];
    const float* bout = (const float*)d_in[17];
    float* out   = (float*)d_out;
    float* woutT = (float*)d_ws;    // 750 floats = 3000 B

    prep_woutT<<<dim3(3), dim3(256), 0, stream>>>(Wout, woutT);

    const int nb = in_sizes[0] / 27;          // 1048576, multiple of 64
    dim3 grid(nb / 64);                        // 16384 blocks of 192 threads
    actor_fused<<<grid, dim3(192), 0, stream>>>(
        spatial,
        Wmx, bmx, Wnx, bnx,
        Wmy, bmy, Wny, bny,
        Wmz, bmz, Wnz, bnz,
        Wlin, blin, woutT, bout,
        out);
}